// Round 3
// baseline (218.518 us; speedup 1.0000x reference)
//
#include <hip/hip_runtime.h>
#include <hip/hip_fp16.h>
#include <cstdint>

#define FDIM 128
#define XSTR 136   // padded row stride in f16 elems (+8 elems = 16 B)
#define NROWTILE 128
#define WCHUNKS ((FDIM * XSTR * 2) / 1024)       // 34 x 1KB chunks per W image
#define CSRS 128   // padded CSR slots per node (Binom(800K,1/50K) max ~40)

typedef __attribute__((ext_vector_type(8))) _Float16 half8;
typedef __attribute__((ext_vector_type(2))) _Float16 h2;
typedef __attribute__((ext_vector_type(16))) float float16;

#if defined(__has_builtin)
#if __has_builtin(__builtin_amdgcn_fdot2)
#define HAVE_FDOT2 1
#endif
#endif

__device__ __forceinline__ void gload_lds16(const void* g, void* s) {
    __builtin_amdgcn_global_load_lds(
        (const __attribute__((address_space(1))) void*)g,
        (__attribute__((address_space(3))) void*)s, 16, 0, 0);
}

__device__ __forceinline__ h2 as_h2(unsigned u) {
    union { unsigned u; h2 h; } c; c.u = u; return c.h;
}
__device__ __forceinline__ float2 h2_to_f2(unsigned u) {
    __half2 h = *(__half2*)&u;
    return __half22float2(h);
}

// ---------------------------------------------------------------------------
// edges_k: W convert+transpose + padded-CSR edge insert (histogram IS the
// scatter). x->f16 conversion moved INTO gemm (XH intermediate deleted).
// Grid = E threads.
// ---------------------------------------------------------------------------
__global__ __launch_bounds__(256) void edges_k(
    const int* __restrict__ ei, int E,
    const float* __restrict__ Wq, const float* __restrict__ Wk,
    const float* __restrict__ Wv, __half* __restrict__ WTH,
    int* __restrict__ deg, int* __restrict__ csr, int N)
{
    int idx = blockIdx.x * 256 + threadIdx.x;

    if (idx < 3 * FDIM * FDIM) {                // W convert+transpose (tiny)
        int mat = idx >> 14;
        int m = idx & 16383;
        int k = m >> 7;
        int nn = m & 127;
        const float* __restrict__ W = (mat == 0) ? Wq : (mat == 1) ? Wk : Wv;
        WTH[(size_t)mat * FDIM * XSTR + nn * XSTR + k] =
            __float2half_rn(W[k * FDIM + nn]);
    }

    if (idx < E) {
        int row = ei[idx];          // target
        int col = ei[E + idx];      // source
        int slot = atomicAdd(&deg[row], 1);
        if (slot < CSRS) csr[(row << 7) + slot] = col;
    }
}

// ---------------------------------------------------------------------------
// MFMA GEMM v2 (f16), mat-fused: grid = nblk blocks; each block stages its
// x row-tile ONCE (f32 -> f16 reg-convert -> LDS, same __float2half_rn bits
// as before) then loops mat = 0..2 reusing xs. ws holds W during MFMA and is
// reused post-MFMA as the coalescing store buffer (4 syncs per mat).
// XH re-read x3 eliminated: pipeline reads x 25.6 MB once instead of
// writing+reading a 13.6 MB intermediate 1x+3x. 391 blocks, 2 blocks/CU ->
// all co-resident, single occupancy round.
// Outputs unchanged: Q -> f16 Qb[N][128]; K,V -> interleaved KV uint2[N][64].
// ---------------------------------------------------------------------------
__global__ __launch_bounds__(256) void gemm_mfma_k(
    const float* __restrict__ x, const __half* __restrict__ WTH,
    const float* __restrict__ bq, const float* __restrict__ bk,
    const float* __restrict__ bias,
    __half* __restrict__ Qb, uint2* __restrict__ KV, int N)
{
    __shared__ __half xs[NROWTILE * XSTR];
    __shared__ __half ws[FDIM * XSTR];

    const int tid  = threadIdx.x;
    const int wave = tid >> 6;
    const int lane = tid & 63;
    const int r0   = blockIdx.x * NROWTILE;

    // issue W(mat=0) async stage first so it overlaps the x convert
    for (int c = wave; c < WCHUNKS; c += 4)
        gload_lds16((const char*)WTH + c * 1024 + lane * 16, (char*)ws + c * 1024);

    // stage x tile: 128 rows x 32 float4 = 4096 float4s, 16 per thread
    #pragma unroll
    for (int it = 0; it < 16; ++it) {
        int idx = it * 256 + tid;
        int row = idx >> 5;
        int c = (idx & 31) << 2;
        float4 v = make_float4(0.f, 0.f, 0.f, 0.f);
        if (r0 + row < N) v = *(const float4*)(x + (size_t)(r0 + row) * FDIM + c);
        __half h[4] = {__float2half_rn(v.x), __float2half_rn(v.y),
                       __float2half_rn(v.z), __float2half_rn(v.w)};
        *(ushort4*)(xs + row * XSTR + c) = *(ushort4*)h;
    }

    const int mrow = lane & 31;    // A row within 32-tile / B,C col within 32
    const int half = lane >> 5;    // 0/1
    const int arow = wave * 32 + mrow;

    for (int mat = 0; mat < 3; ++mat) {
        __syncthreads();           // ws (and xs on first iter) staged

        float16 acc[4];
        #pragma unroll
        for (int nt = 0; nt < 4; ++nt)
            #pragma unroll
            for (int r = 0; r < 16; ++r) acc[nt][r] = 0.f;

        #pragma unroll
        for (int ks = 0; ks < 8; ++ks) {
            const int ko = ks * 16 + half * 8;
            half8 ah = *(const half8*)(xs + arow * XSTR + ko);
            #pragma unroll
            for (int nt = 0; nt < 4; ++nt) {
                half8 bh = *(const half8*)(ws + (nt * 32 + mrow) * XSTR + ko);
                acc[nt] = __builtin_amdgcn_mfma_f32_32x32x16_f16(ah, bh, acc[nt], 0, 0, 0);
            }
        }

        __syncthreads();           // all ds_reads of ws done -> reuse as staging

        // stage outputs to ws; bias + relu applied.
        // C/D layout: col=lane&31 (+32*nt), row=(reg&3)+8*(reg>>2)+4*half (+32*wave)
        const float* bvec = (mat == 0) ? bq : (mat == 1) ? bk : bias;
        #pragma unroll
        for (int nt = 0; nt < 4; ++nt) {
            const int col = nt * 32 + mrow;
            const float bb = bvec[col];
            #pragma unroll
            for (int reg = 0; reg < 16; ++reg) {
                int rl = wave * 32 + (reg & 3) + 8 * (reg >> 2) + 4 * half;
                float v = acc[nt][reg] + bb;
                if (mat < 2) v = fmaxf(v, 0.f);
                ws[rl * XSTR + col] = __float2half_rn(v);
            }
        }
        __syncthreads();

        if (mat == 0) {
            // Qb: 128 rows x 256 B contiguous -> uint4 per thread, 8 passes
            #pragma unroll
            for (int it = 0; it < 8; ++it) {
                int idx = it * 256 + tid;
                int row = idx >> 4;
                int c = (idx & 15) * 8;
                uint4 v = *(const uint4*)(ws + row * XSTR + c);
                if (r0 + row < N)
                    *(uint4*)(Qb + (size_t)(r0 + row) * FDIM + c) = v;
            }
        } else {
            // KV halves: pair p -> 4B at row*512B + p*8B + (mat==2 ? 4 : 0)
            __half* kvh = (__half*)KV;
            const int sub = (mat == 2) ? 2 : 0;
            #pragma unroll
            for (int it = 0; it < 32; ++it) {
                int idx = it * 256 + tid;
                int row = idx >> 6;
                int p = idx & 63;
                unsigned v = *(const unsigned*)(ws + row * XSTR + 2 * p);
                if (r0 + row < N)
                    *(unsigned*)(kvh + (size_t)(r0 + row) * 256 + p * 4 + sub) = v;
            }
        }
        __syncthreads();           // ws free for next mat's W stage

        if (mat < 2) {
            const char* wbase = (const char*)(WTH + (size_t)(mat + 1) * FDIM * XSTR);
            for (int c = wave; c < WCHUNKS; c += 4)
                gload_lds16(wbase + c * 1024 + lane * 16, (char*)ws + c * 1024);
        }
    }
}

// ---------------------------------------------------------------------------
// Aggregation (unchanged from round 2 — at its traffic roofline):
// one wave per node, dynamic block scheduling, full 8-wide gather batches
// with gated tail (s = 0 for inactive slots; index forced to row 0).
// ---------------------------------------------------------------------------
__global__ __launch_bounds__(256) void aggregate_k(
    const __half* __restrict__ Qb, const uint2* __restrict__ KV,
    const int* __restrict__ deg, const int* __restrict__ csr,
    float* __restrict__ out, int N)
{
    const int lane = threadIdx.x & 63;
    int n = blockIdx.x * 4 + (threadIdx.x >> 6);
    if (n >= N) return;
    n = __builtin_amdgcn_readfirstlane(n);

    int d = __builtin_amdgcn_readfirstlane(deg[n]);
    if (d > CSRS) d = CSRS;
    const int off   = n << 7;                 // padded CSR base
    const int total = d + 1;                  // + self loop

    const unsigned qu = *(const unsigned*)(Qb + (size_t)n * FDIM + 2 * lane);
    const h2 q2 = as_h2(qu);
#ifndef HAVE_FDOT2
    const float2 qf = h2_to_f2(qu);
#endif

    float acc0 = 0.f, acc1 = 0.f, lsum = 0.f;

    int idxbuf[8];
    #pragma unroll
    for (int u = 0; u < 8; ++u)
        idxbuf[u] = (u == 0) ? n : ((u < total) ? csr[off + u - 1] : 0);

    for (int t = 0; t < total; t += 8) {
        uint2 kv[8];
        #pragma unroll
        for (int u = 0; u < 8; ++u)
            kv[u] = KV[(((unsigned)idxbuf[u]) << 6) + lane];
        #pragma unroll
        for (int u = 0; u < 8; ++u) {         // refill index ring
            int nx = t + 8 + u;
            idxbuf[u] = (nx < total) ? csr[off + nx - 1] : 0;
        }
        #pragma unroll
        for (int u = 0; u < 8; ++u) {
#ifdef HAVE_FDOT2
            float p = __builtin_amdgcn_fdot2(as_h2(kv[u].x), q2, 0.0f, false);
#else
            float2 kf = h2_to_f2(kv[u].x);
            float p = qf.x * kf.x + qf.y * kf.y;
#endif
            p += __shfl_xor(p, 1);
            p += __shfl_xor(p, 2);
            p += __shfl_xor(p, 4);            // 8-lane head group reduced
            float s = (t + u < total) ? __expf(p) : 0.f;   // gated tail
            float2 vf = h2_to_f2(kv[u].y);
            lsum += s;
            acc0 += s * vf.x;
            acc1 += s * vf.y;
        }
    }

    const float inv = 1.0f / lsum;
    float2 o;
    o.x = acc0 * inv;
    o.y = acc1 * inv;
    *(float2*)(out + (size_t)n * FDIM + 2 * lane) = o;
}

// ---------------------------------------------------------------------------
extern "C" void kernel_launch(void* const* d_in, const int* in_sizes, int n_in,
                              void* d_out, int out_size, void* d_ws, size_t ws_size,
                              hipStream_t stream)
{
    const float* x    = (const float*)d_in[0];
    const int*   ei   = (const int*)d_in[1];
    const float* Wq   = (const float*)d_in[2];
    const float* bq   = (const float*)d_in[3];
    const float* Wk   = (const float*)d_in[4];
    const float* bk   = (const float*)d_in[5];
    const float* Wv   = (const float*)d_in[6];
    const float* bias = (const float*)d_in[7];   // final bias, folded into V
    float* out = (float*)d_out;

    const int N = in_sizes[0] / FDIM;
    const int E = in_sizes[1] / 2;
    const int nblk = (N + NROWTILE - 1) / NROWTILE;

    // workspace layout (~65 MB; XH intermediate removed)
    __half* WTH = (__half*)d_ws;                          // 3 x 128 x 136 f16
    __half* Qb  = WTH + (size_t)3 * FDIM * XSTR;          // N x 128 f16
    uint2*  KV  = (uint2*)(Qb + (size_t)N * FDIM);        // N x 64 x 8B
    int* deg    = (int*)(KV + (size_t)N * 64);            // N
    int* csr    = deg + N;                                // N x 128

    (void)hipMemsetAsync(deg, 0, (size_t)N * sizeof(int), stream);

    edges_k<<<(E + 255) / 256, 256, 0, stream>>>(
        ei, E, Wq, Wk, Wv, WTH, deg, csr, N);

    gemm_mfma_k<<<nblk, 256, 0, stream>>>(
        x, WTH, bq, bk, bias, Qb, KV, N);

    aggregate_k<<<(N + 3) / 4, 256, 0, stream>>>(Qb, KV, deg, csr, out, N);
}

// Round 4
// 205.545 us; speedup vs baseline: 1.0631x; 1.0631x over previous
//
#include <hip/hip_runtime.h>
#include <hip/hip_fp16.h>
#include <cstdint>

#define FDIM 128
#define XSTR 136   // padded row stride in f16 elems (+8 elems = 16 B)
#define NROWTILE 128
#define WCHUNKS ((FDIM * XSTR * 2) / 1024)       // 34 x 1KB chunks per W image
#define CSRS 128   // padded CSR slots per node (Binom(800K,1/50K) max ~40)

typedef __attribute__((ext_vector_type(8))) _Float16 half8;
typedef __attribute__((ext_vector_type(2))) _Float16 h2;
typedef __attribute__((ext_vector_type(16))) float float16;

#if defined(__has_builtin)
#if __has_builtin(__builtin_amdgcn_fdot2)
#define HAVE_FDOT2 1
#endif
#endif

__device__ __forceinline__ void gload_lds16(const void* g, void* s) {
    __builtin_amdgcn_global_load_lds(
        (const __attribute__((address_space(1))) void*)g,
        (__attribute__((address_space(3))) void*)s, 16, 0, 0);
}

__device__ __forceinline__ h2 as_h2(unsigned u) {
    union { unsigned u; h2 h; } c; c.u = u; return c.h;
}
__device__ __forceinline__ float2 h2_to_f2(unsigned u) {
    __half2 h = *(__half2*)&u;
    return __half22float2(h);
}

// ---------------------------------------------------------------------------
// prep_k: replaces hipMemsetAsync + the old edges_k W-convert.
// Zeroes deg and builds WTH (f16, transposed, padded). ~50K threads, ~3 us.
// ---------------------------------------------------------------------------
__global__ __launch_bounds__(256) void prep_k(
    const float* __restrict__ Wq, const float* __restrict__ Wk,
    const float* __restrict__ Wv, __half* __restrict__ WTH,
    int* __restrict__ deg, int N)
{
    int idx = blockIdx.x * 256 + threadIdx.x;

    if (idx < N) deg[idx] = 0;

    if (idx < 3 * FDIM * FDIM) {                // W convert+transpose (tiny)
        int mat = idx >> 14;
        int m = idx & 16383;
        int k = m >> 7;
        int nn = m & 127;
        const float* __restrict__ W = (mat == 0) ? Wq : (mat == 1) ? Wk : Wv;
        WTH[(size_t)mat * FDIM * XSTR + nn * XSTR + k] =
            __float2half_rn(W[k * FDIM + nn]);
    }
}

// ---------------------------------------------------------------------------
// gemm_edges_k: MFMA GEMM (3 mats, x-tile staged once) FUSED with the
// padded-CSR edge scatter. The scatter (8 edges/thread, grid-stride,
// coalesced ei reads, atomicAdd histogram + scattered 4B store) is issued
// right after x staging; its latency hides under the W stage + 3-mat MFMA
// loop instead of occupying a serial dispatch of its own. Scatter output
// (deg/csr) is consumed only by the NEXT kernel -> no intra-kernel ordering
// needed beyond kernel completion.
// GEMM structure unchanged from round 3 (output bits identical):
// Q -> f16 Qb[N][128]; K,V -> interleaved KV uint2[N][64]; relu on Q,K;
// final bias folded into V. LDS 69.6 KB -> 2 blocks/CU.
// ---------------------------------------------------------------------------
__global__ __launch_bounds__(256) void gemm_edges_k(
    const float* __restrict__ x, const __half* __restrict__ WTH,
    const float* __restrict__ bq, const float* __restrict__ bk,
    const float* __restrict__ bias,
    __half* __restrict__ Qb, uint2* __restrict__ KV,
    const int* __restrict__ ei, int E,
    int* __restrict__ deg, int* __restrict__ csr, int N)
{
    __shared__ __half xs[NROWTILE * XSTR];
    __shared__ __half ws[FDIM * XSTR];

    const int tid  = threadIdx.x;
    const int wave = tid >> 6;
    const int lane = tid & 63;
    const int r0   = blockIdx.x * NROWTILE;

    // issue W(mat=0) async stage first so it overlaps the x convert + scatter
    for (int c = wave; c < WCHUNKS; c += 4)
        gload_lds16((const char*)WTH + c * 1024 + lane * 16, (char*)ws + c * 1024);

    // stage x tile: 128 rows x 32 float4 = 4096 float4s, 16 per thread
    #pragma unroll
    for (int it = 0; it < 16; ++it) {
        int idx = it * 256 + tid;
        int row = idx >> 5;
        int c = (idx & 31) << 2;
        float4 v = make_float4(0.f, 0.f, 0.f, 0.f);
        if (r0 + row < N) v = *(const float4*)(x + (size_t)(r0 + row) * FDIM + c);
        __half h[4] = {__float2half_rn(v.x), __float2half_rn(v.y),
                       __float2half_rn(v.z), __float2half_rn(v.w)};
        *(ushort4*)(xs + row * XSTR + c) = *(ushort4*)h;
    }

    // edge scatter: grid-stride, ~8 edges/thread. Latency hides under MFMA.
    {
        const int NT = gridDim.x * 256;
        const int gtid = blockIdx.x * 256 + tid;
        for (int e = gtid; e < E; e += NT) {
            int row = ei[e];            // target
            int col = ei[E + e];        // source
            int slot = atomicAdd(&deg[row], 1);
            if (slot < CSRS) csr[(row << 7) + slot] = col;
        }
    }

    const int mrow = lane & 31;    // A row within 32-tile / B,C col within 32
    const int half = lane >> 5;    // 0/1
    const int arow = wave * 32 + mrow;

    for (int mat = 0; mat < 3; ++mat) {
        __syncthreads();           // ws (and xs on first iter) staged

        float16 acc[4];
        #pragma unroll
        for (int nt = 0; nt < 4; ++nt)
            #pragma unroll
            for (int r = 0; r < 16; ++r) acc[nt][r] = 0.f;

        #pragma unroll
        for (int ks = 0; ks < 8; ++ks) {
            const int ko = ks * 16 + half * 8;
            half8 ah = *(const half8*)(xs + arow * XSTR + ko);
            #pragma unroll
            for (int nt = 0; nt < 4; ++nt) {
                half8 bh = *(const half8*)(ws + (nt * 32 + mrow) * XSTR + ko);
                acc[nt] = __builtin_amdgcn_mfma_f32_32x32x16_f16(ah, bh, acc[nt], 0, 0, 0);
            }
        }

        __syncthreads();           // all ds_reads of ws done -> reuse as staging

        // stage outputs to ws; bias + relu applied.
        // C/D layout: col=lane&31 (+32*nt), row=(reg&3)+8*(reg>>2)+4*half (+32*wave)
        const float* bvec = (mat == 0) ? bq : (mat == 1) ? bk : bias;
        #pragma unroll
        for (int nt = 0; nt < 4; ++nt) {
            const int col = nt * 32 + mrow;
            const float bb = bvec[col];
            #pragma unroll
            for (int reg = 0; reg < 16; ++reg) {
                int rl = wave * 32 + (reg & 3) + 8 * (reg >> 2) + 4 * half;
                float v = acc[nt][reg] + bb;
                if (mat < 2) v = fmaxf(v, 0.f);
                ws[rl * XSTR + col] = __float2half_rn(v);
            }
        }
        __syncthreads();

        if (mat == 0) {
            // Qb: 128 rows x 256 B contiguous -> uint4 per thread, 8 passes
            #pragma unroll
            for (int it = 0; it < 8; ++it) {
                int idx = it * 256 + tid;
                int row = idx >> 4;
                int c = (idx & 15) * 8;
                uint4 v = *(const uint4*)(ws + row * XSTR + c);
                if (r0 + row < N)
                    *(uint4*)(Qb + (size_t)(r0 + row) * FDIM + c) = v;
            }
        } else {
            // KV halves: pair p -> 4B at row*512B + p*8B + (mat==2 ? 4 : 0)
            __half* kvh = (__half*)KV;
            const int sub = (mat == 2) ? 2 : 0;
            #pragma unroll
            for (int it = 0; it < 32; ++it) {
                int idx = it * 256 + tid;
                int row = idx >> 6;
                int p = idx & 63;
                unsigned v = *(const unsigned*)(ws + row * XSTR + 2 * p);
                if (r0 + row < N)
                    *(unsigned*)(kvh + (size_t)(r0 + row) * 256 + p * 4 + sub) = v;
            }
        }
        __syncthreads();           // ws free for next mat's W stage

        if (mat < 2) {
            const char* wbase = (const char*)(WTH + (size_t)(mat + 1) * FDIM * XSTR);
            for (int c = wave; c < WCHUNKS; c += 4)
                gload_lds16(wbase + c * 1024 + lane * 16, (char*)ws + c * 1024);
        }
    }
}

// ---------------------------------------------------------------------------
// Aggregation (unchanged — at its traffic/VALU co-limited floor):
// one wave per node, dynamic block scheduling, full 8-wide gather batches
// with gated tail (s = 0 for inactive slots; index forced to row 0).
// ---------------------------------------------------------------------------
__global__ __launch_bounds__(256) void aggregate_k(
    const __half* __restrict__ Qb, const uint2* __restrict__ KV,
    const int* __restrict__ deg, const int* __restrict__ csr,
    float* __restrict__ out, int N)
{
    const int lane = threadIdx.x & 63;
    int n = blockIdx.x * 4 + (threadIdx.x >> 6);
    if (n >= N) return;
    n = __builtin_amdgcn_readfirstlane(n);

    int d = __builtin_amdgcn_readfirstlane(deg[n]);
    if (d > CSRS) d = CSRS;
    const int off   = n << 7;                 // padded CSR base
    const int total = d + 1;                  // + self loop

    const unsigned qu = *(const unsigned*)(Qb + (size_t)n * FDIM + 2 * lane);
    const h2 q2 = as_h2(qu);
#ifndef HAVE_FDOT2
    const float2 qf = h2_to_f2(qu);
#endif

    float acc0 = 0.f, acc1 = 0.f, lsum = 0.f;

    int idxbuf[8];
    #pragma unroll
    for (int u = 0; u < 8; ++u)
        idxbuf[u] = (u == 0) ? n : ((u < total) ? csr[off + u - 1] : 0);

    for (int t = 0; t < total; t += 8) {
        uint2 kv[8];
        #pragma unroll
        for (int u = 0; u < 8; ++u)
            kv[u] = KV[(((unsigned)idxbuf[u]) << 6) + lane];
        #pragma unroll
        for (int u = 0; u < 8; ++u) {         // refill index ring
            int nx = t + 8 + u;
            idxbuf[u] = (nx < total) ? csr[off + nx - 1] : 0;
        }
        #pragma unroll
        for (int u = 0; u < 8; ++u) {
#ifdef HAVE_FDOT2
            float p = __builtin_amdgcn_fdot2(as_h2(kv[u].x), q2, 0.0f, false);
#else
            float2 kf = h2_to_f2(kv[u].x);
            float p = qf.x * kf.x + qf.y * kf.y;
#endif
            p += __shfl_xor(p, 1);
            p += __shfl_xor(p, 2);
            p += __shfl_xor(p, 4);            // 8-lane head group reduced
            float s = (t + u < total) ? __expf(p) : 0.f;   // gated tail
            float2 vf = h2_to_f2(kv[u].y);
            lsum += s;
            acc0 += s * vf.x;
            acc1 += s * vf.y;
        }
    }

    const float inv = 1.0f / lsum;
    float2 o;
    o.x = acc0 * inv;
    o.y = acc1 * inv;
    *(float2*)(out + (size_t)n * FDIM + 2 * lane) = o;
}

// ---------------------------------------------------------------------------
extern "C" void kernel_launch(void* const* d_in, const int* in_sizes, int n_in,
                              void* d_out, int out_size, void* d_ws, size_t ws_size,
                              hipStream_t stream)
{
    const float* x    = (const float*)d_in[0];
    const int*   ei   = (const int*)d_in[1];
    const float* Wq   = (const float*)d_in[2];
    const float* bq   = (const float*)d_in[3];
    const float* Wk   = (const float*)d_in[4];
    const float* bk   = (const float*)d_in[5];
    const float* Wv   = (const float*)d_in[6];
    const float* bias = (const float*)d_in[7];   // final bias, folded into V
    float* out = (float*)d_out;

    const int N = in_sizes[0] / FDIM;
    const int E = in_sizes[1] / 2;
    const int nblk = (N + NROWTILE - 1) / NROWTILE;

    // workspace layout (~65 MB)
    __half* WTH = (__half*)d_ws;                          // 3 x 128 x 136 f16
    __half* Qb  = WTH + (size_t)3 * FDIM * XSTR;          // N x 128 f16
    uint2*  KV  = (uint2*)(Qb + (size_t)N * FDIM);        // N x 64 x 8B
    int* deg    = (int*)(KV + (size_t)N * 64);            // N
    int* csr    = deg + N;                                // N x 128

    // 3 dispatches total: prep -> fused gemm+edges -> aggregate
    int prep_n = N > 3 * FDIM * FDIM ? N : 3 * FDIM * FDIM;
    prep_k<<<(prep_n + 255) / 256, 256, 0, stream>>>(Wq, Wk, Wv, WTH, deg, N);

    gemm_edges_k<<<nblk, 256, 0, stream>>>(
        x, WTH, bq, bk, bias, Qb, KV, ei, E, deg, csr, N);

    aggregate_k<<<(N + 3) / 4, 256, 0, stream>>>(Qb, KV, deg, csr, out, N);
}

// Round 5
// 197.771 us; speedup vs baseline: 1.1049x; 1.0393x over previous
//
#include <hip/hip_runtime.h>
#include <hip/hip_fp16.h>
#include <cstdint>

#define FDIM 128
#define XSTR 136   // padded row stride in f16 elems (+8 elems = 16 B)
#define NROWTILE 128
#define WCHUNKS ((FDIM * XSTR * 2) / 1024)       // 34 x 1KB chunks per W image
#define CSRS 128   // padded CSR slots per node (Binom(800K,1/50K) max ~40)
#define SBLK 120   // scatter-only blocks appended to the gemm grid

typedef __attribute__((ext_vector_type(8))) _Float16 half8;
typedef __attribute__((ext_vector_type(2))) _Float16 h2;
typedef __attribute__((ext_vector_type(16))) float float16;

#if defined(__has_builtin)
#if __has_builtin(__builtin_amdgcn_fdot2)
#define HAVE_FDOT2 1
#endif
#endif

__device__ __forceinline__ void gload_lds16(const void* g, void* s) {
    __builtin_amdgcn_global_load_lds(
        (const __attribute__((address_space(1))) void*)g,
        (__attribute__((address_space(3))) void*)s, 16, 0, 0);
}

__device__ __forceinline__ h2 as_h2(unsigned u) {
    union { unsigned u; h2 h; } c; c.u = u; return c.h;
}
__device__ __forceinline__ float2 h2_to_f2(unsigned u) {
    __half2 h = *(__half2*)&u;
    return __half22float2(h);
}

// ---------------------------------------------------------------------------
// prep_k: zero deg + W f32->f16 transpose into padded WTH. ~3 us.
// ---------------------------------------------------------------------------
__global__ __launch_bounds__(256) void prep_k(
    const float* __restrict__ Wq, const float* __restrict__ Wk,
    const float* __restrict__ Wv, __half* __restrict__ WTH,
    int* __restrict__ deg, int N)
{
    int idx = blockIdx.x * 256 + threadIdx.x;

    if (idx < N) deg[idx] = 0;

    if (idx < 3 * FDIM * FDIM) {                // W convert+transpose (tiny)
        int mat = idx >> 14;
        int m = idx & 16383;
        int k = m >> 7;
        int nn = m & 127;
        const float* __restrict__ W = (mat == 0) ? Wq : (mat == 1) ? Wk : Wv;
        WTH[(size_t)mat * FDIM * XSTR + nn * XSTR + k] =
            __float2half_rn(W[k * FDIM + nn]);
    }
}

// ---------------------------------------------------------------------------
// gemm_edges_k, heterogeneous grid: blocks [0,nblk) run the pure MFMA GEMM
// (round-3 body, no scatter on its critical path); blocks [nblk, nblk+SBLK)
// run ONLY the edge scatter, concurrently, on the wave slots the gemm grid
// leaves free (391+120 = 511 <= 512 resident at 2 blocks/CU). Scatter blocks
// batch 8 edges (8 indep loads -> 8 indep atomics -> 8 stores) for MLP since
// they only have 8 waves/CU of TLP. deg/csr are consumed by the NEXT kernel
// only; atomic slot order is arbitrary (as in all prior rounds).
// GEMM outputs unchanged: Q -> f16 Qb[N][128]; K,V -> interleaved KV
// uint2[N][64]; relu on Q,K; final bias folded into V.
// ---------------------------------------------------------------------------
__global__ __launch_bounds__(256) void gemm_edges_k(
    const float* __restrict__ x, const __half* __restrict__ WTH,
    const float* __restrict__ bq, const float* __restrict__ bk,
    const float* __restrict__ bias,
    __half* __restrict__ Qb, uint2* __restrict__ KV,
    const int* __restrict__ ei, int E,
    int* __restrict__ deg, int* __restrict__ csr, int N, int nblk)
{
    __shared__ __half xs[NROWTILE * XSTR];
    __shared__ __half ws[FDIM * XSTR];

    const int tid  = threadIdx.x;

    if ((int)blockIdx.x >= nblk) {
        // ---------------- scatter-only block ----------------
        const int sb  = blockIdx.x - nblk;           // 0..SBLK-1
        const int t0  = sb * 256 + tid;
        const int NTH = SBLK * 256;
        for (int base = t0; base < E; base += NTH * 8) {
            int er[8], ec[8], sl[8];
            #pragma unroll
            for (int u = 0; u < 8; ++u) {            // 8 indep coalesced loads
                int e = base + u * NTH;
                bool v = (e < E);
                er[u] = v ? ei[e] : -1;
                ec[u] = v ? ei[E + e] : 0;
            }
            #pragma unroll
            for (int u = 0; u < 8; ++u)              // 8 indep atomics in flight
                if (er[u] >= 0) sl[u] = atomicAdd(&deg[er[u]], 1);
            #pragma unroll
            for (int u = 0; u < 8; ++u)              // 8 indep scattered stores
                if (er[u] >= 0 && sl[u] < CSRS)
                    csr[(er[u] << 7) + sl[u]] = ec[u];
        }
        return;
    }

    // ---------------- gemm block (round-3 body) ----------------
    const int wave = tid >> 6;
    const int lane = tid & 63;
    const int r0   = blockIdx.x * NROWTILE;

    // issue W(mat=0) async stage first so it overlaps the x convert
    for (int c = wave; c < WCHUNKS; c += 4)
        gload_lds16((const char*)WTH + c * 1024 + lane * 16, (char*)ws + c * 1024);

    // stage x tile: 128 rows x 32 float4 = 4096 float4s, 16 per thread
    #pragma unroll
    for (int it = 0; it < 16; ++it) {
        int idx = it * 256 + tid;
        int row = idx >> 5;
        int c = (idx & 31) << 2;
        float4 v = make_float4(0.f, 0.f, 0.f, 0.f);
        if (r0 + row < N) v = *(const float4*)(x + (size_t)(r0 + row) * FDIM + c);
        __half h[4] = {__float2half_rn(v.x), __float2half_rn(v.y),
                       __float2half_rn(v.z), __float2half_rn(v.w)};
        *(ushort4*)(xs + row * XSTR + c) = *(ushort4*)h;
    }

    const int mrow = lane & 31;    // A row within 32-tile / B,C col within 32
    const int half = lane >> 5;    // 0/1
    const int arow = wave * 32 + mrow;

    for (int mat = 0; mat < 3; ++mat) {
        __syncthreads();           // ws (and xs on first iter) staged

        float16 acc[4];
        #pragma unroll
        for (int nt = 0; nt < 4; ++nt)
            #pragma unroll
            for (int r = 0; r < 16; ++r) acc[nt][r] = 0.f;

        #pragma unroll
        for (int ks = 0; ks < 8; ++ks) {
            const int ko = ks * 16 + half * 8;
            half8 ah = *(const half8*)(xs + arow * XSTR + ko);
            #pragma unroll
            for (int nt = 0; nt < 4; ++nt) {
                half8 bh = *(const half8*)(ws + (nt * 32 + mrow) * XSTR + ko);
                acc[nt] = __builtin_amdgcn_mfma_f32_32x32x16_f16(ah, bh, acc[nt], 0, 0, 0);
            }
        }

        __syncthreads();           // all ds_reads of ws done -> reuse as staging

        // stage outputs to ws; bias + relu applied.
        // C/D layout: col=lane&31 (+32*nt), row=(reg&3)+8*(reg>>2)+4*half (+32*wave)
        const float* bvec = (mat == 0) ? bq : (mat == 1) ? bk : bias;
        #pragma unroll
        for (int nt = 0; nt < 4; ++nt) {
            const int col = nt * 32 + mrow;
            const float bb = bvec[col];
            #pragma unroll
            for (int reg = 0; reg < 16; ++reg) {
                int rl = wave * 32 + (reg & 3) + 8 * (reg >> 2) + 4 * half;
                float v = acc[nt][reg] + bb;
                if (mat < 2) v = fmaxf(v, 0.f);
                ws[rl * XSTR + col] = __float2half_rn(v);
            }
        }
        __syncthreads();

        if (mat == 0) {
            // Qb: 128 rows x 256 B contiguous -> uint4 per thread, 8 passes
            #pragma unroll
            for (int it = 0; it < 8; ++it) {
                int idx = it * 256 + tid;
                int row = idx >> 4;
                int c = (idx & 15) * 8;
                uint4 v = *(const uint4*)(ws + row * XSTR + c);
                if (r0 + row < N)
                    *(uint4*)(Qb + (size_t)(r0 + row) * FDIM + c) = v;
            }
        } else {
            // KV halves: pair p -> 4B at row*512B + p*8B + (mat==2 ? 4 : 0)
            __half* kvh = (__half*)KV;
            const int sub = (mat == 2) ? 2 : 0;
            #pragma unroll
            for (int it = 0; it < 32; ++it) {
                int idx = it * 256 + tid;
                int row = idx >> 6;
                int p = idx & 63;
                unsigned v = *(const unsigned*)(ws + row * XSTR + 2 * p);
                if (r0 + row < N)
                    *(unsigned*)(kvh + (size_t)(r0 + row) * 256 + p * 4 + sub) = v;
            }
        }
        __syncthreads();           // ws free for next mat's W stage

        if (mat < 2) {
            const char* wbase = (const char*)(WTH + (size_t)(mat + 1) * FDIM * XSTR);
            for (int c = wave; c < WCHUNKS; c += 4)
                gload_lds16(wbase + c * 1024 + lane * 16, (char*)ws + c * 1024);
        }
    }
}

// ---------------------------------------------------------------------------
// Aggregation (frozen — at its traffic/VALU co-limited floor):
// one wave per node, dynamic block scheduling, full 8-wide gather batches
// with gated tail (s = 0 for inactive slots; index forced to row 0).
// ---------------------------------------------------------------------------
__global__ __launch_bounds__(256) void aggregate_k(
    const __half* __restrict__ Qb, const uint2* __restrict__ KV,
    const int* __restrict__ deg, const int* __restrict__ csr,
    float* __restrict__ out, int N)
{
    const int lane = threadIdx.x & 63;
    int n = blockIdx.x * 4 + (threadIdx.x >> 6);
    if (n >= N) return;
    n = __builtin_amdgcn_readfirstlane(n);

    int d = __builtin_amdgcn_readfirstlane(deg[n]);
    if (d > CSRS) d = CSRS;
    const int off   = n << 7;                 // padded CSR base
    const int total = d + 1;                  // + self loop

    const unsigned qu = *(const unsigned*)(Qb + (size_t)n * FDIM + 2 * lane);
    const h2 q2 = as_h2(qu);
#ifndef HAVE_FDOT2
    const float2 qf = h2_to_f2(qu);
#endif

    float acc0 = 0.f, acc1 = 0.f, lsum = 0.f;

    int idxbuf[8];
    #pragma unroll
    for (int u = 0; u < 8; ++u)
        idxbuf[u] = (u == 0) ? n : ((u < total) ? csr[off + u - 1] : 0);

    for (int t = 0; t < total; t += 8) {
        uint2 kv[8];
        #pragma unroll
        for (int u = 0; u < 8; ++u)
            kv[u] = KV[(((unsigned)idxbuf[u]) << 6) + lane];
        #pragma unroll
        for (int u = 0; u < 8; ++u) {         // refill index ring
            int nx = t + 8 + u;
            idxbuf[u] = (nx < total) ? csr[off + nx - 1] : 0;
        }
        #pragma unroll
        for (int u = 0; u < 8; ++u) {
#ifdef HAVE_FDOT2
            float p = __builtin_amdgcn_fdot2(as_h2(kv[u].x), q2, 0.0f, false);
#else
            float2 kf = h2_to_f2(kv[u].x);
            float p = qf.x * kf.x + qf.y * kf.y;
#endif
            p += __shfl_xor(p, 1);
            p += __shfl_xor(p, 2);
            p += __shfl_xor(p, 4);            // 8-lane head group reduced
            float s = (t + u < total) ? __expf(p) : 0.f;   // gated tail
            float2 vf = h2_to_f2(kv[u].y);
            lsum += s;
            acc0 += s * vf.x;
            acc1 += s * vf.y;
        }
    }

    const float inv = 1.0f / lsum;
    float2 o;
    o.x = acc0 * inv;
    o.y = acc1 * inv;
    *(float2*)(out + (size_t)n * FDIM + 2 * lane) = o;
}

// ---------------------------------------------------------------------------
extern "C" void kernel_launch(void* const* d_in, const int* in_sizes, int n_in,
                              void* d_out, int out_size, void* d_ws, size_t ws_size,
                              hipStream_t stream)
{
    const float* x    = (const float*)d_in[0];
    const int*   ei   = (const int*)d_in[1];
    const float* Wq   = (const float*)d_in[2];
    const float* bq   = (const float*)d_in[3];
    const float* Wk   = (const float*)d_in[4];
    const float* bk   = (const float*)d_in[5];
    const float* Wv   = (const float*)d_in[6];
    const float* bias = (const float*)d_in[7];   // final bias, folded into V
    float* out = (float*)d_out;

    const int N = in_sizes[0] / FDIM;
    const int E = in_sizes[1] / 2;
    const int nblk = (N + NROWTILE - 1) / NROWTILE;

    // workspace layout (~65 MB)
    __half* WTH = (__half*)d_ws;                          // 3 x 128 x 136 f16
    __half* Qb  = WTH + (size_t)3 * FDIM * XSTR;          // N x 128 f16
    uint2*  KV  = (uint2*)(Qb + (size_t)N * FDIM);        // N x 64 x 8B
    int* deg    = (int*)(KV + (size_t)N * 64);            // N
    int* csr    = deg + N;                                // N x 128

    // 3 dispatches: prep -> heterogeneous gemm+scatter -> aggregate
    int prep_n = N > 3 * FDIM * FDIM ? N : 3 * FDIM * FDIM;
    prep_k<<<(prep_n + 255) / 256, 256, 0, stream>>>(Wq, Wk, Wv, WTH, deg, N);

    gemm_edges_k<<<nblk + SBLK, 256, 0, stream>>>(
        x, WTH, bq, bk, bias, Qb, KV, ei, E, deg, csr, N, nblk);

    aggregate_k<<<(N + 3) / 4, 256, 0, stream>>>(Qb, KV, deg, csr, out, N);
}